// Round 1
// baseline (293.194 us; speedup 1.0000x reference)
//
#include <hip/hip_runtime.h>
#include <math.h>

// Problem constants (fixed by the reference): N=8, B=4096, D=1024.
#define NN 8
#define BB 4096
#define DD 1024
#define LOG_2PI 1.8378770664093453f

// One block per row b (256 threads x 4 elems = D=1024).
// Per-element 7-step scan carried as (mean m1, var v1, invvar iv1):
//   iv2 = exp(-lv2); v2 = exp(lv2)
//   s = v1 + v2 + 1e-6;  z += (m1-m2)^2 / s + log(s)
//   iv_new = iv1 + iv2; cvar = 1/iv_new
//   m1 = cvar*(m1*iv1 + m2*iv2); v1 = cvar; iv1 = iv_new
// log_z_total[b] = -0.5*(sum_d z + 7*D*LOG_2PI)
__global__ __launch_bounds__(256) void mpc_kernel(
    const float* __restrict__ means,
    const float* __restrict__ logsig,
    float* __restrict__ out_mean,
    float* __restrict__ out_logvar,
    float* __restrict__ out_logz)
{
    const int b = blockIdx.x;
    const int t = threadIdx.x;
    const size_t rowoff = (size_t)b * DD + (size_t)t * 4;
    const size_t plane = (size_t)BB * DD;

    // step 0: initial carry
    float4 m0 = *(const float4*)(means + rowoff);
    float4 l0 = *(const float4*)(logsig + rowoff);

    float m1[4]  = {m0.x, m0.y, m0.z, m0.w};
    float v1[4], iv1[4];
    {
        float l[4] = {l0.x, l0.y, l0.z, l0.w};
#pragma unroll
        for (int j = 0; j < 4; ++j) {
            v1[j]  = __expf(l[j]);
            iv1[j] = __expf(-l[j]);
        }
    }

    float z = 0.0f;

#pragma unroll
    for (int n = 1; n < NN; ++n) {
        const size_t off = (size_t)n * plane + rowoff;
        float4 m2v = *(const float4*)(means + off);
        float4 l2v = *(const float4*)(logsig + off);
        float m2[4] = {m2v.x, m2v.y, m2v.z, m2v.w};
        float l2[4] = {l2v.x, l2v.y, l2v.z, l2v.w};
#pragma unroll
        for (int j = 0; j < 4; ++j) {
            float v2  = __expf(l2[j]);
            float iv2 = __expf(-l2[j]);
            float s   = v1[j] + v2 + 1e-6f;
            float diff = m1[j] - m2[j];
            z += diff * diff * __builtin_amdgcn_rcpf(s) + __logf(s);
            float iv_new = iv1[j] + iv2;
            float cvar   = __builtin_amdgcn_rcpf(iv_new);
            m1[j]  = cvar * (m1[j] * iv1[j] + m2[j] * iv2);
            v1[j]  = cvar;
            iv1[j] = iv_new;
        }
    }

    // elementwise outputs
    float4 om = make_float4(m1[0], m1[1], m1[2], m1[3]);
    float4 ol = make_float4(__logf(v1[0]), __logf(v1[1]),
                            __logf(v1[2]), __logf(v1[3]));
    *(float4*)(out_mean + rowoff)   = om;
    *(float4*)(out_logvar + rowoff) = ol;

    // row reduction of z (256 threads = 4 waves of 64)
#pragma unroll
    for (int o = 32; o > 0; o >>= 1)
        z += __shfl_down(z, o, 64);

    __shared__ float sz[4];
    const int wave = t >> 6;
    const int lane = t & 63;
    if (lane == 0) sz[wave] = z;
    __syncthreads();
    if (t == 0) {
        float total = sz[0] + sz[1] + sz[2] + sz[3];
        out_logz[b] = -0.5f * (total + (float)((NN - 1) * DD) * LOG_2PI);
    }
}

extern "C" void kernel_launch(void* const* d_in, const int* in_sizes, int n_in,
                              void* d_out, int out_size, void* d_ws, size_t ws_size,
                              hipStream_t stream) {
    const float* means  = (const float*)d_in[0];
    const float* logsig = (const float*)d_in[1];
    float* out = (float*)d_out;
    float* out_mean   = out;
    float* out_logvar = out + (size_t)BB * DD;
    float* out_logz   = out + 2 * (size_t)BB * DD;
    mpc_kernel<<<BB, 256, 0, stream>>>(means, logsig, out_mean, out_logvar, out_logz);
}